// Round 2
// baseline (306.706 us; speedup 1.0000x reference)
//
#include <hip/hip_runtime.h>
#include <stdint.h>

typedef __bf16 bf16x8 __attribute__((ext_vector_type(8)));
typedef float f32x4 __attribute__((ext_vector_type(4)));
typedef short short8 __attribute__((ext_vector_type(8)));
typedef float float4_t __attribute__((ext_vector_type(4)));

union FragU { short8 s; bf16x8 b; };

#define DEVI static __device__ __forceinline__

DEVI unsigned int f2bf(float f) {
  unsigned int x = __float_as_uint(f);
  return (x + 0x7fffu + ((x >> 16) & 1u)) >> 16;  // RNE f32->bf16
}
DEVI float bf2f(unsigned int u) { return __uint_as_float(u << 16); }

DEVI short8 pack8(float4_t a, float4_t b) {
  short8 p;
  p[0] = (short)f2bf(a[0]); p[1] = (short)f2bf(a[1]);
  p[2] = (short)f2bf(a[2]); p[3] = (short)f2bf(a[3]);
  p[4] = (short)f2bf(b[0]); p[5] = (short)f2bf(b[1]);
  p[6] = (short)f2bf(b[2]); p[7] = (short)f2bf(b[3]);
  return p;
}

DEVI f32x4 mfma16(bf16x8 a, bf16x8 b, f32x4 c) {
  return __builtin_amdgcn_mfma_f32_16x16x32_bf16(a, b, c, 0, 0, 0);
}

// ---------------------------------------------------------------------------
// Encoder: out[i][d] = sum_k in[i][k] * W[d][k] + bias[d], stored as bf16,
// plus per-row squared norm of the bf16-rounded output (consistency!).
// Block = 256 threads (4 waves), 64 rows per block, K=128, D=128.
// ---------------------------------------------------------------------------
__global__ __launch_bounds__(256) void encode_kernel(
    const float* __restrict__ in, const float* __restrict__ W,
    const float* __restrict__ bias, unsigned short* __restrict__ outh,
    float* __restrict__ outnorm, int M) {
  __shared__ __align__(16) unsigned short Wl[128 * 128];  // bf16, XOR-swizzled

  const int t = threadIdx.x;
  // Stage W (f32 -> bf16) into LDS. Swizzle: 16B slot s at row r stored at s^(r&7).
  {
    int row = t >> 1, half = t & 1;
#pragma unroll
    for (int j = 0; j < 8; ++j) {
      int c0 = half * 64 + j * 8;
      float4_t v0 = *(const float4_t*)(W + row * 128 + c0);
      float4_t v1 = *(const float4_t*)(W + row * 128 + c0 + 4);
      short8 p = pack8(v0, v1);
      int slot = (half * 8 + j) ^ (row & 7);
      *(short8*)((char*)Wl + row * 256 + slot * 16) = p;
    }
  }
  __syncthreads();

  const int lane = t & 63, w = t >> 6;
  const int g = lane >> 4, q = lane & 15;
  const int rowbase = blockIdx.x * 64 + w * 16;

  // A fragments: lane holds in[rowbase+q][kc*32 + g*8 + e], e=0..7 (bf16)
  bf16x8 a[4];
  {
    int arow = rowbase + q;
    bool v = arow < M;
    int ar = v ? arow : 0;
#pragma unroll
    for (int kc = 0; kc < 4; ++kc) {
      const float4_t* p = (const float4_t*)(in + (size_t)ar * 128 + kc * 32 + g * 8);
      float4_t v0 = p[0], v1 = p[1];
      FragU u;
      u.s = pack8(v0, v1);
      if (!v) u.s = short8{0, 0, 0, 0, 0, 0, 0, 0};
      a[kc] = u.b;
    }
  }

  f32x4 acc[8];
#pragma unroll
  for (int nt = 0; nt < 8; ++nt) acc[nt] = f32x4{0.f, 0.f, 0.f, 0.f};

#pragma unroll
  for (int nt = 0; nt < 8; ++nt) {
    int brow = nt * 16 + q;  // row of W (output dim)
#pragma unroll
    for (int kc = 0; kc < 4; ++kc) {
      int slot = (kc * 4 + g) ^ (brow & 7);
      FragU u;
      u.s = *(const short8*)((const char*)Wl + brow * 256 + slot * 16);
      acc[nt] = mfma16(a[kc], u.b, acc[nt]);
    }
  }

  // Epilogue: add bias, round to bf16, store, accumulate squared norm.
  float nsq[4] = {0.f, 0.f, 0.f, 0.f};
#pragma unroll
  for (int nt = 0; nt < 8; ++nt) {
    int col = nt * 16 + q;
    float bv = bias[col];
#pragma unroll
    for (int r = 0; r < 4; ++r) {
      int row = rowbase + g * 4 + r;  // C layout: row=(lane>>4)*4+reg, col=lane&15
      float val = acc[nt][r] + bv;
      unsigned int bfu = f2bf(val);
      float vf = bf2f(bfu);
      nsq[r] += vf * vf;
      if (row < M) outh[(size_t)row * 128 + col] = (unsigned short)bfu;
    }
  }
  // Reduce nsq over the 16 lanes (q dimension) sharing each row.
#pragma unroll
  for (int m = 1; m < 16; m <<= 1) {
#pragma unroll
    for (int r = 0; r < 4; ++r) nsq[r] += __shfl_xor(nsq[r], m, 64);
  }
  if (q == 0) {
#pragma unroll
    for (int r = 0; r < 4; ++r) {
      int row = rowbase + g * 4 + r;
      if (row < M) outnorm[row] = nsq[r];
    }
  }
}

// ---------------------------------------------------------------------------
// Main: per (rowgroup of 128 H-rows, chunk of candidate tiles) accumulate
// class bins: bins[row][c] += sum_{n in chunk, y[n]==c} exp(-dist(row,n)).
// 512 threads = 8 waves; wave w owns rows w*16..w*16+15 of the rowgroup.
// HC tile (64 cand x 128 k, bf16) staged in LDS via global_load_lds with
// pre-swizzled SOURCE (linear LDS dest), XOR-swizzled ds_read.
// ---------------------------------------------------------------------------
__global__ __launch_bounds__(512) void nca_main(
    const unsigned short* __restrict__ H, const float* __restrict__ hnorm,
    const unsigned short* __restrict__ HC, const float* __restrict__ hcnorm,
    const int* __restrict__ y, float* __restrict__ gbins, int B, int N,
    int NT, int CHUNKS) {
  __shared__ __align__(16) unsigned short HCl[64 * 128];  // 16 KB

  const int t = threadIdx.x, lane = t & 63, w = t >> 6;
  const int g = lane >> 4, q = lane & 15;
  const int rg = blockIdx.y, chunk = blockIdx.x;
  const int t0 = (int)(((long long)chunk * NT) / CHUNKS);
  const int t1 = (int)(((long long)(chunk + 1) * NT) / CHUNKS);
  const int rowbase = rg * 128 + w * 16;

  // A fragments for this wave's 16 rows of H (resident whole kernel).
  bf16x8 a[4];
  {
    int arow = rowbase + q;
    bool v = arow < B;
    int ar = v ? arow : 0;
#pragma unroll
    for (int kc = 0; kc < 4; ++kc) {
      FragU u;
      u.s = *(const short8*)(H + (size_t)ar * 128 + kc * 32 + g * 8);
      if (!v) u.s = short8{0, 0, 0, 0, 0, 0, 0, 0};
      a[kc] = u.b;
    }
  }
  float hn[4];
#pragma unroll
  for (int r = 0; r < 4; ++r) {
    int row = rowbase + g * 4 + r;
    hn[r] = (row < B) ? hnorm[row] : 0.f;
  }

  float bins[4][10];
#pragma unroll
  for (int r = 0; r < 4; ++r)
#pragma unroll
    for (int c = 0; c < 10; ++c) bins[r][c] = 0.f;

  for (int tt = t0; tt < t1; ++tt) {
    const int colbase = tt * 64;
    // Stage 64x128 bf16 HC tile: 1024 16B-slots; 512 threads x 2 issues.
    // LDS[row][s] = HC[colbase+row][s ^ (row&7)]  (pre-swizzled source).
#pragma unroll
    for (int i = 0; i < 2; ++i) {
      int SI = t + 512 * i;
      int row = SI >> 4, s = SI & 15;
      int srcslot = s ^ (row & 7);
      int cg = colbase + row;
      if (cg >= N) cg = N - 1;  // clamp; killed later by hcnorm guard
      const unsigned short* src = HC + (size_t)cg * 128 + srcslot * 8;
      char* ldsbase = (char*)HCl + w * 1024 + i * 8192;  // wave-uniform
      __builtin_amdgcn_global_load_lds(
          (const __attribute__((address_space(1))) unsigned int*)src,
          (__attribute__((address_space(3))) unsigned int*)ldsbase, 16, 0, 0);
    }
    __syncthreads();

    f32x4 acc[4];
#pragma unroll
    for (int ns = 0; ns < 4; ++ns) acc[ns] = f32x4{0.f, 0.f, 0.f, 0.f};
#pragma unroll
    for (int ns = 0; ns < 4; ++ns) {
      int brow = ns * 16 + q;  // tile-local candidate row
#pragma unroll
      for (int kc = 0; kc < 4; ++kc) {
        int slot = (kc * 4 + g) ^ (brow & 7);
        FragU u;
        u.s = *(const short8*)((const char*)HCl + brow * 256 + slot * 16);
        acc[ns] = mfma16(a[kc], u.b, acc[ns]);
      }
    }

    // Epilogue: dist -> exp -> class bins.
#pragma unroll
    for (int ns = 0; ns < 4; ++ns) {
      int col = colbase + ns * 16 + q;
      bool v = col < N;
      float cn = v ? hcnorm[col] : 1e30f;
      int cls = v ? y[col] : 0;
      float wgt[4];
#pragma unroll
      for (int r = 0; r < 4; ++r) {
        float d2 = fmaf(-2.f, acc[ns][r], hn[r] + cn);
        d2 = fmaxf(d2, 0.f);
        float dist = sqrtf(d2);
        wgt[r] = __expf(0.f - dist);
      }
#pragma unroll
      for (int c = 0; c < 10; ++c) {
        float mc = (cls == c) ? 1.f : 0.f;
#pragma unroll
        for (int r = 0; r < 4; ++r) bins[r][c] = fmaf(wgt[r], mc, bins[r][c]);
      }
    }
    __syncthreads();
  }

  // Reduce bins across the 16 lanes (q) sharing each row, then atomics.
#pragma unroll
  for (int m = 1; m < 16; m <<= 1) {
#pragma unroll
    for (int r = 0; r < 4; ++r)
#pragma unroll
      for (int c = 0; c < 10; ++c)
        bins[r][c] += __shfl_xor(bins[r][c], m, 64);
  }
  if (q == 0) {
#pragma unroll
    for (int r = 0; r < 4; ++r) {
      int row = rowbase + g * 4 + r;
      if (row < B) {
#pragma unroll
        for (int c = 0; c < 10; ++c)
          atomicAdd(&gbins[row * 10 + c], bins[r][c]);
      }
    }
  }
}

__global__ __launch_bounds__(256) void finalize_kernel(
    const float* __restrict__ gbins, float* __restrict__ out, int B) {
  int row = blockIdx.x * blockDim.x + threadIdx.x;
  if (row >= B) return;
  float s[10], Z = 0.f;
#pragma unroll
  for (int c = 0; c < 10; ++c) {
    s[c] = gbins[row * 10 + c];
    Z += s[c];
  }
  float inv = 1.f / Z;
#pragma unroll
  for (int c = 0; c < 10; ++c) out[row * 10 + c] = logf(fmaf(s[c], inv, 1e-7f));
}

extern "C" void kernel_launch(void* const* d_in, const int* in_sizes, int n_in,
                              void* d_out, int out_size, void* d_ws,
                              size_t ws_size, hipStream_t stream) {
  const float* x = (const float*)d_in[0];
  const float* cx = (const float*)d_in[1];
  const int* cy = (const int*)d_in[2];
  const float* W = (const float*)d_in[3];
  const float* b = (const float*)d_in[4];
  const int B = in_sizes[0] / 128;
  const int N = in_sizes[1] / 128;
  float* out = (float*)d_out;

  char* ws = (char*)d_ws;
  size_t o = 0;
  auto alloc = [&](size_t bytes) {
    size_t r = o;
    o += (bytes + 255) & ~(size_t)255;
    return r;
  };
  unsigned short* HC = (unsigned short*)(ws + alloc((size_t)N * 128 * 2));
  float* hcn = (float*)(ws + alloc((size_t)N * 4));
  unsigned short* H = (unsigned short*)(ws + alloc((size_t)B * 128 * 2));
  float* hn = (float*)(ws + alloc((size_t)B * 4));
  float* gbins = (float*)(ws + alloc((size_t)B * 10 * 4));

  (void)hipMemsetAsync(gbins, 0, (size_t)B * 10 * 4, stream);
  encode_kernel<<<(N + 63) / 64, 256, 0, stream>>>(cx, W, b, HC, hcn, N);
  encode_kernel<<<(B + 63) / 64, 256, 0, stream>>>(x, W, b, H, hn, B);

  const int NT = (N + 63) / 64;
  const int CHUNKS = 128;
  const int RG = (B + 127) / 128;
  dim3 grid(CHUNKS, RG);
  nca_main<<<grid, 512, 0, stream>>>(H, hn, HC, hcn, cy, gbins, B, N, NT,
                                     CHUNKS);
  finalize_kernel<<<(B + 255) / 256, 256, 0, stream>>>(gbins, out, B);
}

// Round 3
// 201.498 us; speedup vs baseline: 1.5221x; 1.5221x over previous
//
#include <hip/hip_runtime.h>
#include <stdint.h>

typedef __bf16 bf16x8 __attribute__((ext_vector_type(8)));
typedef float f32x4 __attribute__((ext_vector_type(4)));
typedef short short8 __attribute__((ext_vector_type(8)));
typedef unsigned short ushort4v __attribute__((ext_vector_type(4)));
typedef float float4_t __attribute__((ext_vector_type(4)));

union FragU { short8 s; bf16x8 b; };

#define DEVI static __device__ __forceinline__

DEVI f32x4 mfma16(bf16x8 a, bf16x8 b, f32x4 c) {
  return __builtin_amdgcn_mfma_f32_16x16x32_bf16(a, b, c, 0, 0, 0);
}

DEVI bf16x8 cvt8(float4_t a, float4_t b) {
  bf16x8 r;
  r[0] = (__bf16)a[0]; r[1] = (__bf16)a[1]; r[2] = (__bf16)a[2]; r[3] = (__bf16)a[3];
  r[4] = (__bf16)b[0]; r[5] = (__bf16)b[1]; r[6] = (__bf16)b[2]; r[7] = (__bf16)b[3];
  return r;
}

// ---------------------------------------------------------------------------
// Setup: (a) W f32 -> bf16 row-major;  (b) pad hcnorm[N..NP) = 1e30;
// (c) YT[16][NP] bf16 one-hot transpose: YT[c][n] = (y[n]==c) ? 1 : 0.
// ---------------------------------------------------------------------------
__global__ __launch_bounds__(256) void setup_kernel(
    const float* __restrict__ W, unsigned short* __restrict__ Wbf,
    const int* __restrict__ y, unsigned short* __restrict__ YT,
    float* __restrict__ hcn, int N, int NP, int bpc) {
  const int bid = blockIdx.x, t = threadIdx.x;
  if (bid < 8) {  // Wbf: 16384 elems = 8 blocks * 256 thr * 8
    int i = (bid * 256 + t) * 8;
    float4_t v0 = *(const float4_t*)(W + i);
    float4_t v1 = *(const float4_t*)(W + i + 4);
    FragU u; u.b = cvt8(v0, v1);
    *(short8*)(Wbf + i) = u.s;
  } else if (bid == 8) {  // hcnorm pad (NP-N < 64)
    int i = N + t;
    if (i < NP) hcn[i] = 1e30f;
  } else {  // YT
    int k = bid - 9;
    int c = k / bpc, j = k - c * bpc;
    int n0 = j * 2048 + t * 8;
    unsigned short* dst = YT + (size_t)c * NP + n0;
#pragma unroll
    for (int e = 0; e < 8; ++e) {
      int n = n0 + e;
      if (n < NP) dst[e] = (n < N && y[n] == c) ? 0x3F80u : 0u;
    }
  }
}

// ---------------------------------------------------------------------------
// Encoder: out[i][d] = sum_k in[i][k]*W[d][k] + b[d] (bf16), + row sq-norm of
// the ROUNDED output. No LDS: W fragments load global->reg (L1/L2-hit).
// Block 256 thr = 4 waves, 64 rows/block.
// ---------------------------------------------------------------------------
__global__ __launch_bounds__(256) void encode_kernel(
    const float* __restrict__ in, const unsigned short* __restrict__ Wbf,
    const float* __restrict__ bias, unsigned short* __restrict__ outh,
    float* __restrict__ outnorm, int M) {
  const int t = threadIdx.x, lane = t & 63, w = t >> 6;
  const int g = lane >> 4, q = lane & 15;
  const int rowbase = blockIdx.x * 64 + w * 16;

  bf16x8 a[4];
  {
    int arow = rowbase + q;
    bool v = arow < M;
    int ar = v ? arow : 0;
#pragma unroll
    for (int kc = 0; kc < 4; ++kc) {
      const float4_t* p = (const float4_t*)(in + (size_t)ar * 128 + kc * 32 + g * 8);
      float4_t v0 = p[0], v1 = p[1];
      FragU u; u.b = cvt8(v0, v1);
      if (!v) u.s = short8{0, 0, 0, 0, 0, 0, 0, 0};
      a[kc] = u.b;
    }
  }

  f32x4 acc[8];
#pragma unroll
  for (int nt = 0; nt < 8; ++nt) acc[nt] = f32x4{0.f, 0.f, 0.f, 0.f};

#pragma unroll
  for (int nt = 0; nt < 8; ++nt) {
#pragma unroll
    for (int kc = 0; kc < 4; ++kc) {
      FragU u;
      u.s = *(const short8*)(Wbf + (size_t)(nt * 16 + q) * 128 + kc * 32 + g * 8);
      acc[nt] = mfma16(a[kc], u.b, acc[nt]);
    }
  }

  float nsq[4] = {0.f, 0.f, 0.f, 0.f};
#pragma unroll
  for (int nt = 0; nt < 8; ++nt) {
    int col = nt * 16 + q;
    float bv = bias[col];
#pragma unroll
    for (int r = 0; r < 4; ++r) {
      int row = rowbase + g * 4 + r;  // D: row=(lane>>4)*4+reg, col=lane&15
      float val = acc[nt][r] + bv;
      __bf16 h = (__bf16)val;
      float vf = (float)h;
      nsq[r] += vf * vf;
      union { __bf16 h; unsigned short u; } cv; cv.h = h;
      if (row < M) outh[(size_t)row * 128 + col] = cv.u;
    }
  }
#pragma unroll
  for (int m = 1; m < 16; m <<= 1) {
#pragma unroll
    for (int r = 0; r < 4; ++r) nsq[r] += __shfl_xor(nsq[r], m, 64);
  }
  if (q == 0) {
#pragma unroll
    for (int r = 0; r < 4; ++r) {
      int row = rowbase + g * 4 + r;
      if (row < M) outnorm[row] = nsq[r];
    }
  }
}

// ---------------------------------------------------------------------------
// Main. Swapped QK: acc = mfma(HC_frag, H_frag) -> lane holds
// P[cand = cb+ns*16+g*4+r][hrow = rowbase+q]. Pooling via second MFMA:
// pool = mfma(YT_frag, wgt_frag, pool) -> lane holds bins[class=g*4+r][hrow=q].
// Double-buffered LDS staging (global_load_lds, pre-swizzled source),
// one barrier per tile, cn/yt prefetched before the MFMA block.
// ---------------------------------------------------------------------------
__global__ __launch_bounds__(512) void nca_main(
    const unsigned short* __restrict__ H, const float* __restrict__ hnorm,
    const unsigned short* __restrict__ HC, const float* __restrict__ hcnorm,
    const unsigned short* __restrict__ YT, float* __restrict__ gbins,
    int B, int N, int NP, int NT, int CHUNKS) {
  __shared__ __align__(16) unsigned short HCl[2][64 * 128];  // 2 x 16 KB

  const int t = threadIdx.x, lane = t & 63, w = t >> 6;
  const int g = lane >> 4, q = lane & 15;
  const int rg = blockIdx.y, chunk = blockIdx.x;
  const int t0 = (int)(((long long)chunk * NT) / CHUNKS);
  const int t1 = (int)(((long long)(chunk + 1) * NT) / CHUNKS);
  const int rowbase = rg * 128 + w * 16;

  // H fragments (B-operand of swapped QK): lane holds H[rowbase+q][kc*32+g*8+e]
  bf16x8 hfrag[4];
  {
    int arow = rowbase + q;
    bool v = arow < B;
    int ar = v ? arow : 0;
#pragma unroll
    for (int kc = 0; kc < 4; ++kc) {
      FragU u;
      u.s = *(const short8*)(H + (size_t)ar * 128 + kc * 32 + g * 8);
      if (!v) u.s = short8{0, 0, 0, 0, 0, 0, 0, 0};
      hfrag[kc] = u.b;
    }
  }
  const int hrow = rowbase + q;
  const float hn = hnorm[hrow < B ? hrow : 0];

  f32x4 pool = f32x4{0.f, 0.f, 0.f, 0.f};

#define STAGE(TT, BUF)                                                        \
  {                                                                           \
    _Pragma("unroll") for (int i = 0; i < 2; ++i) {                           \
      int SI = t + 512 * i;                                                   \
      int row = SI >> 4, s = SI & 15;                                         \
      int srcslot = s ^ (row & 7);                                            \
      int cg = (TT)*64 + row;                                                 \
      if (cg >= N) cg = N - 1;                                                \
      const unsigned short* src = HC + (size_t)cg * 128 + srcslot * 8;        \
      char* ldsbase = (char*)HCl[BUF] + w * 1024 + i * 8192;                  \
      __builtin_amdgcn_global_load_lds(                                       \
          (const __attribute__((address_space(1))) unsigned int*)src,         \
          (__attribute__((address_space(3))) unsigned int*)ldsbase, 16, 0, 0);\
    }                                                                         \
  }

  int cur = 0;
  if (t0 < t1) STAGE(t0, 0);

  for (int tt = t0; tt < t1; ++tt) {
    __syncthreads();  // drains stage(cur) [vmcnt] + prev reads [lgkmcnt]
    if (tt + 1 < t1) STAGE(tt + 1, cur ^ 1);

    const int colbase = tt * 64;
    float4_t cnv[4];
    ushort4v ytv[4];
#pragma unroll
    for (int ns = 0; ns < 4; ++ns) {
      cnv[ns] = *(const float4_t*)(hcnorm + colbase + ns * 16 + g * 4);
      ytv[ns] = *(const ushort4v*)(YT + (size_t)q * NP + colbase + ns * 16 + g * 4);
    }

    f32x4 acc[4];
#pragma unroll
    for (int ns = 0; ns < 4; ++ns) acc[ns] = f32x4{0.f, 0.f, 0.f, 0.f};
#pragma unroll
    for (int ns = 0; ns < 4; ++ns) {
      int brow = ns * 16 + q;
#pragma unroll
      for (int kc = 0; kc < 4; ++kc) {
        int slot = (kc * 4 + g) ^ (brow & 7);
        FragU u;
        u.s = *(const short8*)((const char*)HCl[cur] + brow * 256 + slot * 16);
        acc[ns] = mfma16(u.b, hfrag[kc], acc[ns]);
      }
    }

#pragma unroll
    for (int ns = 0; ns < 4; ++ns) {
      FragU wb; wb.s = short8{0, 0, 0, 0, 0, 0, 0, 0};
#pragma unroll
      for (int r = 0; r < 4; ++r) {
        float d2 = fmaf(-2.f, acc[ns][r], hn + cnv[ns][r]);
        d2 = fmaxf(d2, 0.f);
        float dist = __builtin_amdgcn_sqrtf(d2);
        wb.b[r] = (__bf16)__expf(0.f - dist);
      }
      FragU yb;
      yb.s = short8{(short)ytv[ns][0], (short)ytv[ns][1],
                    (short)ytv[ns][2], (short)ytv[ns][3], 0, 0, 0, 0};
      pool = mfma16(yb.b, wb.b, pool);
    }
    cur ^= 1;
  }

  if (hrow < B) {
#pragma unroll
    for (int r = 0; r < 4; ++r) {
      int c = g * 4 + r;
      if (c < 10) atomicAdd(&gbins[hrow * 10 + c], pool[r]);
    }
  }
#undef STAGE
}

__global__ __launch_bounds__(256) void finalize_kernel(
    const float* __restrict__ gbins, float* __restrict__ out, int B) {
  int row = blockIdx.x * blockDim.x + threadIdx.x;
  if (row >= B) return;
  float s[10], Z = 0.f;
#pragma unroll
  for (int c = 0; c < 10; ++c) {
    s[c] = gbins[row * 10 + c];
    Z += s[c];
  }
  float inv = 1.f / Z;
#pragma unroll
  for (int c = 0; c < 10; ++c) out[row * 10 + c] = logf(fmaf(s[c], inv, 1e-7f));
}

extern "C" void kernel_launch(void* const* d_in, const int* in_sizes, int n_in,
                              void* d_out, int out_size, void* d_ws,
                              size_t ws_size, hipStream_t stream) {
  const float* x = (const float*)d_in[0];
  const float* cx = (const float*)d_in[1];
  const int* cy = (const int*)d_in[2];
  const float* W = (const float*)d_in[3];
  const float* b = (const float*)d_in[4];
  const int B = in_sizes[0] / 128;
  const int N = in_sizes[1] / 128;
  float* out = (float*)d_out;

  const int NT = (N + 63) / 64;
  const int NP = NT * 64;

  char* ws = (char*)d_ws;
  size_t o = 0;
  auto alloc = [&](size_t bytes) {
    size_t r = o;
    o += (bytes + 255) & ~(size_t)255;
    return r;
  };
  unsigned short* HC = (unsigned short*)(ws + alloc((size_t)N * 128 * 2));
  float* hcn = (float*)(ws + alloc((size_t)NP * 4));
  unsigned short* H = (unsigned short*)(ws + alloc((size_t)B * 128 * 2));
  float* hn = (float*)(ws + alloc((size_t)B * 4));
  float* gbins = (float*)(ws + alloc((size_t)B * 10 * 4));
  unsigned short* Wbf = (unsigned short*)(ws + alloc(128 * 128 * 2));
  unsigned short* YT = (unsigned short*)(ws + alloc((size_t)16 * NP * 2));

  (void)hipMemsetAsync(gbins, 0, (size_t)B * 10 * 4, stream);
  const int bpc = (NP + 2047) / 2048;
  setup_kernel<<<9 + 16 * bpc, 256, 0, stream>>>(W, Wbf, cy, YT, hcn, N, NP, bpc);
  encode_kernel<<<(N + 63) / 64, 256, 0, stream>>>(cx, Wbf, b, HC, hcn, N);
  encode_kernel<<<(B + 63) / 64, 256, 0, stream>>>(x, Wbf, b, H, hn, B);

  const int CHUNKS = 192;
  const int RG = (B + 127) / 128;
  dim3 grid(CHUNKS, RG);
  nca_main<<<grid, 512, 0, stream>>>(H, hn, HC, hcn, YT, gbins, B, N, NP, NT,
                                     CHUNKS);
  finalize_kernel<<<(B + 255) / 256, 256, 0, stream>>>(gbins, out, B);
}

// Round 4
// 176.749 us; speedup vs baseline: 1.7353x; 1.1400x over previous
//
#include <hip/hip_runtime.h>
#include <stdint.h>

typedef __bf16 bf16x8 __attribute__((ext_vector_type(8)));
typedef float f32x4 __attribute__((ext_vector_type(4)));
typedef short short8 __attribute__((ext_vector_type(8)));
typedef unsigned int uint2v __attribute__((ext_vector_type(2)));
typedef float float4_t __attribute__((ext_vector_type(4)));

union FragU { short8 s; bf16x8 b; };
union YbU { uint2v u2[2]; bf16x8 b; };

#define DEVI static __device__ __forceinline__

DEVI f32x4 mfma16(bf16x8 a, bf16x8 b, f32x4 c) {
  return __builtin_amdgcn_mfma_f32_16x16x32_bf16(a, b, c, 0, 0, 0);
}

DEVI bf16x8 cvt8(float4_t a, float4_t b) {
  bf16x8 r;
  r[0] = (__bf16)a[0]; r[1] = (__bf16)a[1]; r[2] = (__bf16)a[2]; r[3] = (__bf16)a[3];
  r[4] = (__bf16)b[0]; r[5] = (__bf16)b[1]; r[6] = (__bf16)b[2]; r[7] = (__bf16)b[3];
  return r;
}

// ---------------------------------------------------------------------------
// Setup: (a) W f32->bf16; (b) pad hcnorm[N..NP)=1e30; (c) YT[16][NP] one-hot.
// ---------------------------------------------------------------------------
__global__ __launch_bounds__(256) void setup_kernel(
    const float* __restrict__ W, unsigned short* __restrict__ Wbf,
    const int* __restrict__ y, unsigned short* __restrict__ YT,
    float* __restrict__ hcn, int N, int NP, int bpc) {
  const int bid = blockIdx.x, t = threadIdx.x;
  if (bid < 8) {
    int i = (bid * 256 + t) * 8;
    float4_t v0 = *(const float4_t*)(W + i);
    float4_t v1 = *(const float4_t*)(W + i + 4);
    FragU u; u.b = cvt8(v0, v1);
    *(short8*)(Wbf + i) = u.s;
  } else if (bid == 8) {
    int i = N + t;
    if (i < NP) hcn[i] = 1e30f;
  } else {
    int k = bid - 9;
    int c = k / bpc, j = k - c * bpc;
    int n0 = j * 2048 + t * 8;
    unsigned short* dst = YT + (size_t)c * NP + n0;
#pragma unroll
    for (int e = 0; e < 8; ++e) {
      int n = n0 + e;
      if (n < NP) dst[e] = (n < N && y[n] == c) ? 0x3F80u : 0u;
    }
  }
}

// ---------------------------------------------------------------------------
// Fused encoder for both candidate_x and x. Block of 256 thr handles 64 rows.
// ---------------------------------------------------------------------------
__global__ __launch_bounds__(256) void encode_kernel(
    const float* __restrict__ inA, const float* __restrict__ inB,
    const unsigned short* __restrict__ Wbf, const float* __restrict__ bias,
    unsigned short* __restrict__ outA, float* __restrict__ normA,
    unsigned short* __restrict__ outB, float* __restrict__ normB,
    int MA, int MB, int NBA) {
  const float* in;
  unsigned short* outh;
  float* outnorm;
  int M, blk;
  if ((int)blockIdx.x < NBA) {
    in = inA; outh = outA; outnorm = normA; M = MA; blk = blockIdx.x;
  } else {
    in = inB; outh = outB; outnorm = normB; M = MB; blk = blockIdx.x - NBA;
  }
  const int t = threadIdx.x, lane = t & 63, w = t >> 6;
  const int g = lane >> 4, q = lane & 15;
  const int rowbase = blk * 64 + w * 16;

  bf16x8 a[4];
  {
    int arow = rowbase + q;
    bool v = arow < M;
    int ar = v ? arow : 0;
#pragma unroll
    for (int kc = 0; kc < 4; ++kc) {
      const float4_t* p = (const float4_t*)(in + (size_t)ar * 128 + kc * 32 + g * 8);
      float4_t v0 = p[0], v1 = p[1];
      FragU u; u.b = cvt8(v0, v1);
      if (!v) u.s = short8{0, 0, 0, 0, 0, 0, 0, 0};
      a[kc] = u.b;
    }
  }

  f32x4 acc[8];
#pragma unroll
  for (int nt = 0; nt < 8; ++nt) acc[nt] = f32x4{0.f, 0.f, 0.f, 0.f};
#pragma unroll
  for (int nt = 0; nt < 8; ++nt) {
#pragma unroll
    for (int kc = 0; kc < 4; ++kc) {
      FragU u;
      u.s = *(const short8*)(Wbf + (size_t)(nt * 16 + q) * 128 + kc * 32 + g * 8);
      acc[nt] = mfma16(a[kc], u.b, acc[nt]);
    }
  }

  float nsq[4] = {0.f, 0.f, 0.f, 0.f};
#pragma unroll
  for (int nt = 0; nt < 8; ++nt) {
    int col = nt * 16 + q;
    float bv = bias[col];
#pragma unroll
    for (int r = 0; r < 4; ++r) {
      int row = rowbase + g * 4 + r;
      float val = acc[nt][r] + bv;
      __bf16 h = (__bf16)val;
      float vf = (float)h;
      nsq[r] += vf * vf;
      union { __bf16 h; unsigned short u; } cv; cv.h = h;
      if (row < M) outh[(size_t)row * 128 + col] = cv.u;
    }
  }
#pragma unroll
  for (int m = 1; m < 16; m <<= 1) {
#pragma unroll
    for (int r = 0; r < 4; ++r) nsq[r] += __shfl_xor(nsq[r], m, 64);
  }
  if (q == 0) {
#pragma unroll
    for (int r = 0; r < 4; ++r) {
      int row = rowbase + g * 4 + r;
      if (row < M) outnorm[row] = nsq[r];
    }
  }
}

// ---------------------------------------------------------------------------
// Main. Swapped QK (lane holds P[cand][hrow]); class-pool via second MFMA.
// Wave owns 32 H-rows (2 fragment sets) -> each LDS b128 feeds 2 MFMAs.
// Block = 8 waves = 256 rows; RG=2 covers B=512. Partials to part[] (no
// atomics): part[chunk][row][16], one float4 store per lane.
// ---------------------------------------------------------------------------
__global__ __launch_bounds__(512, 4) void nca_main(
    const unsigned short* __restrict__ H, const float* __restrict__ hnorm,
    const unsigned short* __restrict__ HC, const float* __restrict__ hcnorm,
    const unsigned short* __restrict__ YT, float* __restrict__ part,
    int B, int BP, int N, int NP, int NT, int CHUNKS) {
  __shared__ __align__(16) unsigned short HCl[2][64 * 128];  // 2 x 16 KB

  const int t = threadIdx.x, lane = t & 63, w = t >> 6;
  const int g = lane >> 4, q = lane & 15;
  const int rg = blockIdx.y, chunk = blockIdx.x;
  const int t0 = (int)(((long long)chunk * NT) / CHUNKS);
  const int t1 = (int)(((long long)(chunk + 1) * NT) / CHUNKS);

  // Two H fragment sets: rows rg*256 + s*128 + w*16 + q.
  bf16x8 hfrag[2][4];
  float hn[2];
  int hrow[2];
#pragma unroll
  for (int s = 0; s < 2; ++s) {
    hrow[s] = rg * 256 + s * 128 + w * 16 + q;
    bool v = hrow[s] < B;
    int ar = v ? hrow[s] : 0;
#pragma unroll
    for (int kc = 0; kc < 4; ++kc) {
      FragU u;
      u.s = *(const short8*)(H + (size_t)ar * 128 + kc * 32 + g * 8);
      if (!v) u.s = short8{0, 0, 0, 0, 0, 0, 0, 0};
      hfrag[s][kc] = u.b;
    }
    hn[s] = hnorm[ar];
  }

  f32x4 pool0 = f32x4{0.f, 0.f, 0.f, 0.f};
  f32x4 pool1 = f32x4{0.f, 0.f, 0.f, 0.f};

#define STAGE(TT, BUF)                                                        \
  {                                                                           \
    _Pragma("unroll") for (int i = 0; i < 2; ++i) {                           \
      int SI = t + 512 * i;                                                   \
      int row = SI >> 4, s = SI & 15;                                         \
      int srcslot = s ^ (row & 7);                                            \
      int cg = (TT)*64 + row;                                                 \
      if (cg >= N) cg = N - 1;                                                \
      const unsigned short* src = HC + (size_t)cg * 128 + srcslot * 8;        \
      char* ldsbase = (char*)HCl[BUF] + w * 1024 + i * 8192;                  \
      __builtin_amdgcn_global_load_lds(                                       \
          (const __attribute__((address_space(1))) unsigned int*)src,         \
          (__attribute__((address_space(3))) unsigned int*)ldsbase, 16, 0, 0);\
    }                                                                         \
  }

  int cur = 0;
  if (t0 < t1) STAGE(t0, 0);

  for (int tt = t0; tt < t1; ++tt) {
    __syncthreads();  // stage(tt) landed; prev tile reads drained
    if (tt + 1 < t1) STAGE(tt + 1, cur ^ 1);

    const int colbase = tt * 64;
    float4_t cnv[4];
    uint2v ytu[4];
#pragma unroll
    for (int ns = 0; ns < 4; ++ns) {
      cnv[ns] = *(const float4_t*)(hcnorm + colbase + ns * 16 + g * 4);
      ytu[ns] = *(const uint2v*)(YT + (size_t)q * NP + colbase + ns * 16 + g * 4);
    }

#pragma unroll
    for (int ns = 0; ns < 4; ++ns) {
      int brow = ns * 16 + q;
      f32x4 a0 = f32x4{0.f, 0.f, 0.f, 0.f};
      f32x4 a1 = f32x4{0.f, 0.f, 0.f, 0.f};
#pragma unroll
      for (int kc = 0; kc < 4; ++kc) {
        int slot = (kc * 4 + g) ^ (brow & 7);
        FragU u;
        u.s = *(const short8*)((const char*)HCl[cur] + brow * 256 + slot * 16);
        a0 = mfma16(u.b, hfrag[0][kc], a0);
        a1 = mfma16(u.b, hfrag[1][kc], a1);
      }
      FragU wb0, wb1;
      wb0.s = short8{0, 0, 0, 0, 0, 0, 0, 0};
      wb1.s = short8{0, 0, 0, 0, 0, 0, 0, 0};
#pragma unroll
      for (int r = 0; r < 4; ++r) {
        float d20 = fmaf(-2.f, a0[r], hn[0] + cnv[ns][r]);
        float d21 = fmaf(-2.f, a1[r], hn[1] + cnv[ns][r]);
        d20 = fmaxf(d20, 0.f);
        d21 = fmaxf(d21, 0.f);
        float di0 = __builtin_amdgcn_sqrtf(d20);
        float di1 = __builtin_amdgcn_sqrtf(d21);
        wb0.b[r] = (__bf16)__expf(0.f - di0);
        wb1.b[r] = (__bf16)__expf(0.f - di1);
      }
      YbU yb;
      yb.u2[0] = ytu[ns];
      yb.u2[1] = uint2v{0u, 0u};
      pool0 = mfma16(yb.b, wb0.b, pool0);
      pool1 = mfma16(yb.b, wb1.b, pool1);
    }
    cur ^= 1;
  }
#undef STAGE

  // Coalesced partial store: part[chunk][hrow][16], lane writes float4 at c=g*4.
  if (hrow[0] < B)
    *(f32x4*)(part + ((size_t)chunk * BP + hrow[0]) * 16 + g * 4) = pool0;
  if (hrow[1] < B)
    *(f32x4*)(part + ((size_t)chunk * BP + hrow[1]) * 16 + g * 4) = pool1;
}

// One wave per row: sum over CHUNKS partials, softmax-denominator, log.
__global__ __launch_bounds__(64) void finalize_kernel(
    const float* __restrict__ part, float* __restrict__ out, int B, int BP,
    int CHUNKS) {
  const int row = blockIdx.x, t = threadIdx.x;
  const int c = t & 15, grp = t >> 4;  // 4 groups
  float s = 0.f;
  for (int j = grp; j < CHUNKS; j += 4)
    s += part[((size_t)j * BP + row) * 16 + c];
  s += __shfl_xor(s, 16, 64);
  s += __shfl_xor(s, 32, 64);
  float Z = 0.f;
#pragma unroll
  for (int cc = 0; cc < 10; ++cc) Z += __shfl(s, cc, 64);
  if (t < 10) out[row * 10 + t] = logf(fmaf(s, 1.f / Z, 1e-7f));
}

extern "C" void kernel_launch(void* const* d_in, const int* in_sizes, int n_in,
                              void* d_out, int out_size, void* d_ws,
                              size_t ws_size, hipStream_t stream) {
  const float* x = (const float*)d_in[0];
  const float* cx = (const float*)d_in[1];
  const int* cy = (const int*)d_in[2];
  const float* W = (const float*)d_in[3];
  const float* b = (const float*)d_in[4];
  const int B = in_sizes[0] / 128;
  const int N = in_sizes[1] / 128;
  float* out = (float*)d_out;

  const int NT = (N + 63) / 64;
  const int NP = NT * 64;
  const int RG = (B + 255) / 256;
  const int BP = RG * 256;

  char* ws = (char*)d_ws;
  size_t o = 0;
  auto alloc = [&](size_t bytes) {
    size_t r = o;
    o += (bytes + 255) & ~(size_t)255;
    return r;
  };
  unsigned short* HC = (unsigned short*)(ws + alloc((size_t)N * 128 * 2));
  float* hcn = (float*)(ws + alloc((size_t)NP * 4));
  unsigned short* H = (unsigned short*)(ws + alloc((size_t)B * 128 * 2));
  float* hn = (float*)(ws + alloc((size_t)B * 4));
  unsigned short* Wbf = (unsigned short*)(ws + alloc(128 * 128 * 2));
  unsigned short* YT = (unsigned short*)(ws + alloc((size_t)16 * NP * 2));

  // Partials: fit CHUNKS to remaining workspace (cap 256, floor 32).
  size_t avail = (ws_size > o) ? (ws_size - o) : 0;
  int CHUNKS = (int)(avail / ((size_t)BP * 16 * 4));
  if (CHUNKS > 256) CHUNKS = 256;
  if (CHUNKS < 32) CHUNKS = 32;  // (would need 1.3 MB; ws is far larger)
  float* part = (float*)(ws + alloc((size_t)CHUNKS * BP * 16 * 4));

  const int bpc = (NP + 2047) / 2048;
  setup_kernel<<<9 + 16 * bpc, 256, 0, stream>>>(W, Wbf, cy, YT, hcn, N, NP, bpc);

  const int NBA = (N + 63) / 64, NBB = (B + 63) / 64;
  encode_kernel<<<NBA + NBB, 256, 0, stream>>>(cx, x, Wbf, b, HC, hcn, H, hn,
                                               N, B, NBA);

  dim3 grid(CHUNKS, RG);
  nca_main<<<grid, 512, 0, stream>>>(H, hn, HC, hcn, YT, part, B, BP, N, NP,
                                     NT, CHUNKS);
  finalize_kernel<<<B, 64, 0, stream>>>(part, out, B, BP, CHUNKS);
}